// Round 7
// baseline (191.968 us; speedup 1.0000x reference)
//
#include <hip/hip_runtime.h>

#define NCLASS 100
#define HID    768
#define BATCH  512
#define SG     8
#define NPAIR  6
#define BH     (BATCH * HID)

// Deterministic per-class sample list (wave 0 of each block).
__device__ __forceinline__ void build_list(const int* __restrict__ y, int c,
                                           int* slist, int* scnt, int t) {
    if (t < 64) {
        int n = 0;
        for (int r = 0; r < BATCH / 64; ++r) {
            const int b = r * 64 + t;
            const bool hit = (y[b] == c);
            const unsigned long long mask = __ballot(hit);
            if (hit) slist[n + __popcll(mask & ((1ull << t) - 1ull))] = b;
            n += __popcll(mask);
        }
        if (t == 0) *scnt = n;
    }
}

// ---------------------------------------------------------------------------
// Fused kernel. Block (c, pr) owns panel pair {11-pr, pr} (13 chunks total
// each -> perfectly balanced; all 600 blocks co-resident).
// Per panel J=[64g,64g+64):
//  phase A: t_j = sum_{h<j} x_h M[h,j] + d_j x_j + 1e-3 (X - x_j)
//           (column strip rows 0..col0+63 streamed from HBM, 256B/row)
//  phase B: pout[g][b][k] = sum_{j in J, j>k} M[k,j] t_j for k in [0,col0+64)
//           (same strip re-read row-parallel, L2/L3-hot; t_J from LDS)
// k3 sums pout over panels and adds d_k t_k + 1e-3 (Tt - t_k).
// ---------------------------------------------------------------------------
__global__ __launch_bounds__(256, 4) void fusedAB(
    const float* __restrict__ x, const int* __restrict__ y,
    const float* __restrict__ M, float* __restrict__ T, float* __restrict__ P)
{
    const int c  = blockIdx.x;
    const int pr = blockIdx.y;
    const int t  = threadIdx.x;

    __shared__ int   slist[BATCH];
    __shared__ int   scnt;
    __shared__ float xs[SG][HID];            // 24 KB
    __shared__ float Xs[SG];
    __shared__ float red[4][16][4][SG + 1];  // 9.2 KB, padded
    __shared__ float t_lds[SG][64];          // 2 KB
    __shared__ float dj2[2][64];

    build_list(y, c, slist, &scnt, t);
    __syncthreads();
    const int cnt = scnt;
    if (cnt == 0) return;

    const float* __restrict__ Mc = M + (size_t)c * HID * HID;
    const int wv = t >> 6, ln = t & 63;
    const int hg = t >> 4, jq = t & 15;      // phase A map
    const int rr = t >> 2, qt = t & 3;       // phase B map

    const int gtab[2] = {11 - pr, pr};       // big panel first
    if (t < 128) {
        const int pi = t >> 6;
        const int jg = gtab[pi] * 64 + (t & 63);
        dj2[pi][t & 63] = fmaxf(Mc[(size_t)jg * HID + jg], 1e-3f);
    }

    for (int g0 = 0; g0 < cnt; g0 += SG) {
        const int gs = min(SG, cnt - g0);
        __syncthreads();                      // prev group done; dj2 visible
        // stage x rows: wave wv stages samples 2wv, 2wv+1; also row-sums X
        #pragma unroll
        for (int ss = 0; ss < 2; ++ss) {
            const int s = 2 * wv + ss;
            const int b = slist[g0 + (s < gs ? s : 0)];
            const float4* xr = (const float4*)(x + (size_t)b * HID);
            const float4 v0 = xr[ln], v1 = xr[ln + 64], v2 = xr[ln + 128];
            *(float4*)&xs[s][ln * 4]       = v0;
            *(float4*)&xs[s][ln * 4 + 256] = v1;
            *(float4*)&xs[s][ln * 4 + 512] = v2;
            float pX = ((v0.x + v0.y) + (v0.z + v0.w))
                     + ((v1.x + v1.y) + (v1.z + v1.w))
                     + ((v2.x + v2.y) + (v2.z + v2.w));
            #pragma unroll
            for (int off = 32; off; off >>= 1) pX += __shfl_xor(pX, off);
            if (ln == 0) Xs[s] = pX;
        }
        __syncthreads();                      // xs, Xs visible

        for (int pi = 0; pi < 2; ++pi) {
            const int g    = gtab[pi];
            const int col0 = g * 64;
            const float* __restrict__ Mpan = Mc + col0 + jq * 4;

            // ---------------- phase A ----------------
            float tp[4][SG];
            #pragma unroll
            for (int jj = 0; jj < 4; ++jj)
                #pragma unroll
                for (int s = 0; s < SG; ++s) tp[jj][s] = 0.f;

            for (int hb = 0; hb < col0; hb += 64) {   // bulk rows h < col0
                float4 ma[4];
                #pragma unroll
                for (int m = 0; m < 4; ++m)
                    ma[m] = *(const float4*)(Mpan + (size_t)(hb + hg + 16 * m) * HID);
                #pragma unroll
                for (int m = 0; m < 4; ++m) {
                    const int h = hb + hg + 16 * m;
                    #pragma unroll
                    for (int s = 0; s < SG; ++s) {
                        const float xv = xs[s][h];
                        tp[0][s] = fmaf(xv, ma[m].x, tp[0][s]);
                        tp[1][s] = fmaf(xv, ma[m].y, tp[1][s]);
                        tp[2][s] = fmaf(xv, ma[m].z, tp[2][s]);
                        tp[3][s] = fmaf(xv, ma[m].w, tp[3][s]);
                    }
                }
            }
            {   // peeled diagonal square: strict h < j
                float4 ma[4];
                #pragma unroll
                for (int m = 0; m < 4; ++m) {
                    const int hrel = hg + 16 * m;
                    ma[m] = *(const float4*)(Mpan + (size_t)(col0 + hrel) * HID);
                    if (4 * jq + 0 <= hrel) ma[m].x = 0.f;
                    if (4 * jq + 1 <= hrel) ma[m].y = 0.f;
                    if (4 * jq + 2 <= hrel) ma[m].z = 0.f;
                    if (4 * jq + 3 <= hrel) ma[m].w = 0.f;
                }
                #pragma unroll
                for (int m = 0; m < 4; ++m) {
                    const int h = col0 + hg + 16 * m;
                    #pragma unroll
                    for (int s = 0; s < SG; ++s) {
                        const float xv = xs[s][h];
                        tp[0][s] = fmaf(xv, ma[m].x, tp[0][s]);
                        tp[1][s] = fmaf(xv, ma[m].y, tp[1][s]);
                        tp[2][s] = fmaf(xv, ma[m].z, tp[2][s]);
                        tp[3][s] = fmaf(xv, ma[m].w, tp[3][s]);
                    }
                }
            }
            // reduce the 4 row-subgroups within each wave (lane bits 4,5)
            #pragma unroll
            for (int mm = 16; mm <= 32; mm <<= 1)
                #pragma unroll
                for (int jj = 0; jj < 4; ++jj)
                    #pragma unroll
                    for (int s = 0; s < SG; ++s)
                        tp[jj][s] += __shfl_xor(tp[jj][s], mm);
            if (ln < 16) {
                #pragma unroll
                for (int jj = 0; jj < 4; ++jj)
                    #pragma unroll
                    for (int s = 0; s < SG; ++s)
                        red[wv][ln][jj][s] = tp[jj][s];
            }
            __syncthreads();                  // red visible
            // finalize t_J: thread t -> col j = t&63, samples (t>>6)*2+ss
            {
                const int j = t & 63, jq2 = j >> 2, jj2 = j & 3;
                const int jg = col0 + j;
                #pragma unroll
                for (int ss = 0; ss < 2; ++ss) {
                    const int s = (t >> 6) * 2 + ss;
                    const float u = (red[0][jq2][jj2][s] + red[1][jq2][jj2][s])
                                  + (red[2][jq2][jj2][s] + red[3][jq2][jj2][s]);
                    const float xj = xs[s][jg];
                    const float tj = u + dj2[pi][j] * xj + 1e-3f * (Xs[s] - xj);
                    t_lds[s][j] = tj;         // always defined (dup sample)
                    if (s < gs)
                        T[(size_t)slist[g0 + s] * HID + jg] = tj;
                }
            }
            __syncthreads();                  // t_lds ready

            // ---------------- phase B ----------------
            float* __restrict__ Pg = P + (size_t)g * BH;
            for (int kb = 0; kb < col0 + 64; kb += 64) {
                const int k = kb + rr;
                const float* __restrict__ rowp = Mc + (size_t)k * HID + col0;
                float4 mv[4];
                #pragma unroll
                for (int u = 0; u < 4; ++u)
                    mv[u] = ((const float4*)rowp)[qt + 4 * u];
                if (kb == col0) {             // diag chunk: keep j > k only
                    #pragma unroll
                    for (int u = 0; u < 4; ++u) {
                        const int jb = 4 * (qt + 4 * u);
                        if (jb + 0 <= rr) mv[u].x = 0.f;
                        if (jb + 1 <= rr) mv[u].y = 0.f;
                        if (jb + 2 <= rr) mv[u].z = 0.f;
                        if (jb + 3 <= rr) mv[u].w = 0.f;
                    }
                }
                float acc[SG];
                #pragma unroll
                for (int s = 0; s < SG; ++s) acc[s] = 0.f;
                #pragma unroll
                for (int s = 0; s < SG; ++s) {
                    #pragma unroll
                    for (int u = 0; u < 4; ++u) {
                        const float4 tv = *(const float4*)&t_lds[s][4 * (qt + 4 * u)];
                        acc[s] = fmaf(mv[u].x, tv.x, acc[s]);
                        acc[s] = fmaf(mv[u].y, tv.y, acc[s]);
                        acc[s] = fmaf(mv[u].z, tv.z, acc[s]);
                        acc[s] = fmaf(mv[u].w, tv.w, acc[s]);
                    }
                }
                #pragma unroll
                for (int s = 0; s < SG; ++s) {
                    acc[s] += __shfl_xor(acc[s], 1);
                    acc[s] += __shfl_xor(acc[s], 2);
                }
                if (qt == 0) {
                    for (int s = 0; s < gs; ++s)
                        Pg[(size_t)slist[g0 + s] * HID + k] = acc[s];
                }
            }
            __syncthreads();                  // t_lds reads done before reuse
        }
    }
}

// ---------------------------------------------------------------------------
// k3: out[b,k] = sum_{p >= k/64} pout[p][b][k] + d_k t_k + 1e-3 (Tt - t_k)
// One block per sample; p-loop trip count is wave-uniform (k>>6 == wave id).
// ---------------------------------------------------------------------------
__global__ __launch_bounds__(256, 4) void k3(
    const int* __restrict__ y, const float* __restrict__ M,
    const float* __restrict__ T, const float* __restrict__ P,
    float* __restrict__ out)
{
    const int b = blockIdx.x;
    const int t = threadIdx.x;
    const int c = y[b];

    __shared__ float wred[4];
    const float* __restrict__ tb = T + (size_t)b * HID;
    const float t0 = tb[t], t1 = tb[t + 256], t2 = tb[t + 512];
    float s = t0 + t1 + t2;
    #pragma unroll
    for (int off = 32; off; off >>= 1) s += __shfl_xor(s, off);
    if ((t & 63) == 0) wred[t >> 6] = s;
    __syncthreads();
    const float Tt = (wred[0] + wred[1]) + (wred[2] + wred[3]);

    const float* __restrict__ Mc = M + (size_t)c * HID * HID;
    const float tv[3] = {t0, t1, t2};
    #pragma unroll
    for (int q = 0; q < 3; ++q) {
        const int k = t + 256 * q;
        float pk = 0.f;
        for (int p = k >> 6; p < 12; ++p)
            pk += P[(size_t)p * BH + (size_t)b * HID + k];
        const float dk = fmaxf(Mc[(size_t)k * HID + k], 1e-3f);
        out[(size_t)b * HID + k] = pk + dk * tv[q] + 1e-3f * (Tt - tv[q]);
    }
}

extern "C" void kernel_launch(void* const* d_in, const int* in_sizes, int n_in,
                              void* d_out, int out_size, void* d_ws, size_t ws_size,
                              hipStream_t stream) {
    const float* x = (const float*)d_in[0];
    const int*   y = (const int*)d_in[1];
    const float* M = (const float*)d_in[2];
    float* out = (float*)d_out;
    float* T   = (float*)d_ws;                 // 1.5 MiB
    float* P   = (float*)d_ws + BH;            // 12 panel slots, 18 MiB

    fusedAB<<<dim3(NCLASS, NPAIR), 256, 0, stream>>>(x, y, M, T, P);
    k3<<<dim3(BATCH), 256, 0, stream>>>(y, M, T, P, out);
}

// Round 8
// 146.329 us; speedup vs baseline: 1.3119x; 1.3119x over previous
//
#include <hip/hip_runtime.h>

#define NCLASS 100
#define HID    768
#define BATCH  512
#define SG     16
#define BH     (BATCH * HID)

// Uniform tile tables (big-work-first dispatch order).
// kA block = (class, y): column panel g (64 cols), row slice h (256 rows).
__constant__ int gA_tab[24] = {3,4,5,6,7,7,8,8,9,9,10,10,11,11,11, 2,6,10, 1,5,9, 0,4,8};
__constant__ int hA_tab[24] = {0,0,0,0,0,1,0,1,0,1, 0, 1, 0, 1, 2, 0,1, 2, 0,1,2, 0,1,2};
// kB block = (class, y): row panel q (64 rows), col slice v (256 cols).
__constant__ int qB_tab[24] = {0,0,1,1,2,2,3,3,4,5,6,7, 0,4,8, 1,5,9, 2,6,10, 3,7,11};
__constant__ int vB_tab[24] = {1,2,1,2,1,2,1,2,2,2,2,2, 0,1,2, 0,1,2, 0, 1, 2, 0,1, 2};

// Deterministic per-class sample list (wave 0 of each block).
__device__ __forceinline__ void build_list(const int* __restrict__ y, int c,
                                           int* slist, int* scnt, int t) {
    if (t < 64) {
        int n = 0;
        for (int r = 0; r < BATCH / 64; ++r) {
            const int b = r * 64 + t;
            const bool hit = (y[b] == c);
            const unsigned long long mask = __ballot(hit);
            if (hit) slist[n + __popcll(mask & ((1ull << t) - 1ull))] = b;
            n += __popcll(mask);
        }
        if (t == 0) *scnt = n;
    }
}

// ---------------------------------------------------------------------------
// kA: partial t.  Tp[h][b][col0+j] = sum over rows [256h, 256h+rows) of
// x[b,row]*M[row, col0+j] (strict row<col inside the diagonal square).
// Thread map: hg=t>>4 (16 rows/chunk), jq=t&15 (16 col-quads); SG=16 samples.
// No barriers inside the streaming loop; 8 float4 loads in flight.
// ---------------------------------------------------------------------------
__global__ __launch_bounds__(256, 3) void kA(
    const float* __restrict__ x, const int* __restrict__ y,
    const float* __restrict__ M, float* __restrict__ Tp)
{
    const int t    = threadIdx.x;
    const int c    = blockIdx.x;
    const int g    = gA_tab[blockIdx.y], h = hA_tab[blockIdx.y];
    const int col0 = g * 64, row0 = h * 256;
    const bool hasdiag = (h == (g >> 2));
    const int rows = min(256, 64 * (g + 1) - row0);
    const int bulk = hasdiag ? rows - 64 : rows;

    __shared__ int   slist[BATCH];
    __shared__ int   scnt;
    __shared__ float xs[SG][256];            // 16 KB
    __shared__ float red[4][16][4][SG + 1];  // 17.4 KB, padded

    build_list(y, c, slist, &scnt, t);
    __syncthreads();
    const int cnt = scnt;
    if (cnt == 0) return;

    const float* __restrict__ Mc   = M + (size_t)c * HID * HID;
    const float* __restrict__ Mpan = Mc + (size_t)row0 * HID + col0 + (t & 15) * 4;
    const int hg = t >> 4, jq = t & 15, wv = t >> 6, ln = t & 63;

    for (int g0 = 0; g0 < cnt; g0 += SG) {
        const int gs = min(SG, cnt - g0);
        __syncthreads();                      // prev group fully done
        {   // stage x rows [row0, row0+256): sample s by threads (s, l)
            const int s = t >> 4, l = t & 15;
            const int b = slist[g0 + (s < gs ? s : 0)];
            const float4* xr = (const float4*)(x + (size_t)b * HID + row0);
            const float4 v0 = xr[l * 4], v1 = xr[l * 4 + 1],
                         v2 = xr[l * 4 + 2], v3 = xr[l * 4 + 3];
            *(float4*)&xs[s][l * 16]      = v0;
            *(float4*)&xs[s][l * 16 + 4]  = v1;
            *(float4*)&xs[s][l * 16 + 8]  = v2;
            *(float4*)&xs[s][l * 16 + 12] = v3;
        }
        __syncthreads();

        float tp[4][SG];
        #pragma unroll
        for (int jj = 0; jj < 4; ++jj)
            #pragma unroll
            for (int s = 0; s < SG; ++s) tp[jj][s] = 0.f;

        int r = 0;
        for (; r + 128 <= bulk; r += 128) {   // 8 loads in flight
            float4 ma[4], mb[4];
            #pragma unroll
            for (int m = 0; m < 4; ++m)
                ma[m] = *(const float4*)(Mpan + (size_t)(r + hg + 16 * m) * HID);
            #pragma unroll
            for (int m = 0; m < 4; ++m)
                mb[m] = *(const float4*)(Mpan + (size_t)(r + 64 + hg + 16 * m) * HID);
            #pragma unroll
            for (int m = 0; m < 4; ++m) {
                const int lr = r + hg + 16 * m;
                #pragma unroll
                for (int s = 0; s < SG; ++s) {
                    const float xv = xs[s][lr];
                    tp[0][s] = fmaf(xv, ma[m].x, tp[0][s]);
                    tp[1][s] = fmaf(xv, ma[m].y, tp[1][s]);
                    tp[2][s] = fmaf(xv, ma[m].z, tp[2][s]);
                    tp[3][s] = fmaf(xv, ma[m].w, tp[3][s]);
                }
            }
            #pragma unroll
            for (int m = 0; m < 4; ++m) {
                const int lr = r + 64 + hg + 16 * m;
                #pragma unroll
                for (int s = 0; s < SG; ++s) {
                    const float xv = xs[s][lr];
                    tp[0][s] = fmaf(xv, mb[m].x, tp[0][s]);
                    tp[1][s] = fmaf(xv, mb[m].y, tp[1][s]);
                    tp[2][s] = fmaf(xv, mb[m].z, tp[2][s]);
                    tp[3][s] = fmaf(xv, mb[m].w, tp[3][s]);
                }
            }
        }
        if (r < bulk) {                       // one remaining 64-row chunk
            float4 ma[4];
            #pragma unroll
            for (int m = 0; m < 4; ++m)
                ma[m] = *(const float4*)(Mpan + (size_t)(r + hg + 16 * m) * HID);
            #pragma unroll
            for (int m = 0; m < 4; ++m) {
                const int lr = r + hg + 16 * m;
                #pragma unroll
                for (int s = 0; s < SG; ++s) {
                    const float xv = xs[s][lr];
                    tp[0][s] = fmaf(xv, ma[m].x, tp[0][s]);
                    tp[1][s] = fmaf(xv, ma[m].y, tp[1][s]);
                    tp[2][s] = fmaf(xv, ma[m].z, tp[2][s]);
                    tp[3][s] = fmaf(xv, ma[m].w, tp[3][s]);
                }
            }
        }
        if (hasdiag) {                        // diagonal square: strict row<col
            float4 ma[4];
            #pragma unroll
            for (int m = 0; m < 4; ++m) {
                const int hrel = hg + 16 * m;
                ma[m] = *(const float4*)(Mpan + (size_t)(bulk + hrel) * HID);
                if (4 * jq + 0 <= hrel) ma[m].x = 0.f;
                if (4 * jq + 1 <= hrel) ma[m].y = 0.f;
                if (4 * jq + 2 <= hrel) ma[m].z = 0.f;
                if (4 * jq + 3 <= hrel) ma[m].w = 0.f;
            }
            #pragma unroll
            for (int m = 0; m < 4; ++m) {
                const int lr = bulk + hg + 16 * m;
                #pragma unroll
                for (int s = 0; s < SG; ++s) {
                    const float xv = xs[s][lr];
                    tp[0][s] = fmaf(xv, ma[m].x, tp[0][s]);
                    tp[1][s] = fmaf(xv, ma[m].y, tp[1][s]);
                    tp[2][s] = fmaf(xv, ma[m].z, tp[2][s]);
                    tp[3][s] = fmaf(xv, ma[m].w, tp[3][s]);
                }
            }
        }
        // reduce 4 hg-subgroups within each wave (lane bits 4,5)
        #pragma unroll
        for (int mm = 16; mm <= 32; mm <<= 1)
            #pragma unroll
            for (int jj = 0; jj < 4; ++jj)
                #pragma unroll
                for (int s = 0; s < SG; ++s)
                    tp[jj][s] += __shfl_xor(tp[jj][s], mm);
        if (ln < 16) {
            #pragma unroll
            for (int jj = 0; jj < 4; ++jj)
                #pragma unroll
                for (int s = 0; s < SG; ++s)
                    red[wv][ln][jj][s] = tp[jj][s];
        }
        __syncthreads();                      // red visible
        {   // write: thread t -> col j=t&63, samples (t>>6)*4+ss
            const int j = t & 63, jq2 = j >> 2, jj2 = j & 3;
            #pragma unroll
            for (int ss = 0; ss < 4; ++ss) {
                const int s = (t >> 6) * 4 + ss;
                if (s < gs) {
                    const float u = (red[0][jq2][jj2][s] + red[1][jq2][jj2][s])
                                  + (red[2][jq2][jj2][s] + red[3][jq2][jj2][s]);
                    Tp[(size_t)h * BH + (size_t)slist[g0 + s] * HID + col0 + j] = u;
                }
            }
        }
    }
}

// ---------------------------------------------------------------------------
// kT: assemble t.  t[b,j] = sum_{h<=j>>8} Tp[h][b][j] + d_j x_j + 1e-3(X-x_j).
// One block per sample (512 blocks).
// ---------------------------------------------------------------------------
__global__ __launch_bounds__(256) void kT(
    const float* __restrict__ x, const int* __restrict__ y,
    const float* __restrict__ M, const float* __restrict__ Tp,
    float* __restrict__ T)
{
    const int b = blockIdx.x, t = threadIdx.x;
    const int c = y[b];
    __shared__ float wred[4];

    const float* __restrict__ xb = x + (size_t)b * HID;
    const float xv0 = xb[t], xv1 = xb[t + 256], xv2 = xb[t + 512];
    float sx = xv0 + xv1 + xv2;
    #pragma unroll
    for (int off = 32; off; off >>= 1) sx += __shfl_xor(sx, off);
    if ((t & 63) == 0) wred[t >> 6] = sx;
    __syncthreads();
    const float X = (wred[0] + wred[1]) + (wred[2] + wred[3]);

    const float* __restrict__ Mc = M + (size_t)c * HID * HID;
    const size_t bh = (size_t)b * HID;
    const float u0 = Tp[bh + t];
    const float u1 = Tp[bh + t + 256] + Tp[BH + bh + t + 256];
    const float u2 = Tp[bh + t + 512] + Tp[BH + bh + t + 512] + Tp[2 * (size_t)BH + bh + t + 512];
    const float uu[3] = {u0, u1, u2};
    const float xx[3] = {xv0, xv1, xv2};
    #pragma unroll
    for (int qi = 0; qi < 3; ++qi) {
        const int j = t + 256 * qi;
        const float dj = fmaxf(Mc[(size_t)j * (HID + 1)], 1e-3f);
        T[bh + j] = uu[qi] + dj * xx[qi] + 1e-3f * (X - xx[qi]);
    }
}

// ---------------------------------------------------------------------------
// kB: partial out.  P[v][b][k0+kl] = sum over cols [c0, c0+w) (strictly j>k
// inside the diag chunk) of M[k, j] * t[b, j].
// Thread map: kr=t>>4 (16 rows x 4 m), cg=t&15 (16 col-quads); SG=16 samples.
// ---------------------------------------------------------------------------
__global__ __launch_bounds__(256, 3) void kB(
    const int* __restrict__ y, const float* __restrict__ M,
    const float* __restrict__ T, float* __restrict__ P)
{
    const int t  = threadIdx.x;
    const int c  = blockIdx.x;
    const int q  = qB_tab[blockIdx.y], v = vB_tab[blockIdx.y];
    const int k0 = 64 * q;
    const int c0 = max(256 * v, k0);
    const int w  = 256 * (v + 1) - c0;
    const bool hasdiag = (c0 == k0);

    __shared__ int   slist[BATCH];
    __shared__ int   scnt;
    __shared__ float ts[SG][256];             // 16 KB
    __shared__ float ob[SG][65];              // padded

    build_list(y, c, slist, &scnt, t);
    __syncthreads();
    const int cnt = scnt;
    if (cnt == 0) return;

    const float* __restrict__ Mc = M + (size_t)c * HID * HID;
    const int kr = t >> 4, cg = t & 15;
    const float* __restrict__ Mrow = Mc + (size_t)(k0 + kr) * HID + c0 + cg * 4;
    const int jl0 = (c0 - 256 * v) + cg * 4;  // ts-local col of this thread

    for (int g0 = 0; g0 < cnt; g0 += SG) {
        const int gs = min(SG, cnt - g0);
        __syncthreads();                      // prev group fully done
        {   // stage t cols [256v, 256v+256)
            const int s = t >> 4, l = t & 15;
            const int b = slist[g0 + (s < gs ? s : 0)];
            const float4* tr = (const float4*)(T + (size_t)b * HID + 256 * v);
            const float4 v0 = tr[l * 4], v1 = tr[l * 4 + 1],
                         v2 = tr[l * 4 + 2], v3 = tr[l * 4 + 3];
            *(float4*)&ts[s][l * 16]      = v0;
            *(float4*)&ts[s][l * 16 + 4]  = v1;
            *(float4*)&ts[s][l * 16 + 8]  = v2;
            *(float4*)&ts[s][l * 16 + 12] = v3;
        }
        __syncthreads();

        float acc[4][SG];
        #pragma unroll
        for (int m = 0; m < 4; ++m)
            #pragma unroll
            for (int s = 0; s < SG; ++s) acc[m][s] = 0.f;

        {   // peeled first chunk (masked if diag-crossing)
            float4 mq[4];
            #pragma unroll
            for (int m = 0; m < 4; ++m)
                mq[m] = *(const float4*)(Mrow + (size_t)(16 * m) * HID);
            if (hasdiag) {
                #pragma unroll
                for (int m = 0; m < 4; ++m) {
                    const int krel = kr + 16 * m;
                    if (4 * cg + 0 <= krel) mq[m].x = 0.f;
                    if (4 * cg + 1 <= krel) mq[m].y = 0.f;
                    if (4 * cg + 2 <= krel) mq[m].z = 0.f;
                    if (4 * cg + 3 <= krel) mq[m].w = 0.f;
                }
            }
            #pragma unroll
            for (int s = 0; s < SG; ++s) {
                const float4 tv = *(const float4*)&ts[s][jl0];
                #pragma unroll
                for (int m = 0; m < 4; ++m) {
                    acc[m][s] = fmaf(mq[m].x, tv.x, acc[m][s]);
                    acc[m][s] = fmaf(mq[m].y, tv.y, acc[m][s]);
                    acc[m][s] = fmaf(mq[m].z, tv.z, acc[m][s]);
                    acc[m][s] = fmaf(mq[m].w, tv.w, acc[m][s]);
                }
            }
        }
        int cb = 64;
        for (; cb + 128 <= w; cb += 128) {    // 8 loads in flight
            float4 ma[4], mb[4];
            #pragma unroll
            for (int m = 0; m < 4; ++m)
                ma[m] = *(const float4*)(Mrow + (size_t)(16 * m) * HID + cb);
            #pragma unroll
            for (int m = 0; m < 4; ++m)
                mb[m] = *(const float4*)(Mrow + (size_t)(16 * m) * HID + cb + 64);
            #pragma unroll
            for (int s = 0; s < SG; ++s) {
                const float4 tv = *(const float4*)&ts[s][jl0 + cb];
                #pragma unroll
                for (int m = 0; m < 4; ++m) {
                    acc[m][s] = fmaf(ma[m].x, tv.x, acc[m][s]);
                    acc[m][s] = fmaf(ma[m].y, tv.y, acc[m][s]);
                    acc[m][s] = fmaf(ma[m].z, tv.z, acc[m][s]);
                    acc[m][s] = fmaf(ma[m].w, tv.w, acc[m][s]);
                }
            }
            #pragma unroll
            for (int s = 0; s < SG; ++s) {
                const float4 tv = *(const float4*)&ts[s][jl0 + cb + 64];
                #pragma unroll
                for (int m = 0; m < 4; ++m) {
                    acc[m][s] = fmaf(mb[m].x, tv.x, acc[m][s]);
                    acc[m][s] = fmaf(mb[m].y, tv.y, acc[m][s]);
                    acc[m][s] = fmaf(mb[m].z, tv.z, acc[m][s]);
                    acc[m][s] = fmaf(mb[m].w, tv.w, acc[m][s]);
                }
            }
        }
        if (cb < w) {                         // one remaining 64-col chunk
            float4 ma[4];
            #pragma unroll
            for (int m = 0; m < 4; ++m)
                ma[m] = *(const float4*)(Mrow + (size_t)(16 * m) * HID + cb);
            #pragma unroll
            for (int s = 0; s < SG; ++s) {
                const float4 tv = *(const float4*)&ts[s][jl0 + cb];
                #pragma unroll
                for (int m = 0; m < 4; ++m) {
                    acc[m][s] = fmaf(ma[m].x, tv.x, acc[m][s]);
                    acc[m][s] = fmaf(ma[m].y, tv.y, acc[m][s]);
                    acc[m][s] = fmaf(ma[m].z, tv.z, acc[m][s]);
                    acc[m][s] = fmaf(ma[m].w, tv.w, acc[m][s]);
                }
            }
        }
        // reduce 16 col-quads (lane bits 0..3)
        #pragma unroll
        for (int mm = 1; mm <= 8; mm <<= 1)
            #pragma unroll
            for (int m = 0; m < 4; ++m)
                #pragma unroll
                for (int s = 0; s < SG; ++s)
                    acc[m][s] += __shfl_xor(acc[m][s], mm);
        if (cg == 0) {
            #pragma unroll
            for (int m = 0; m < 4; ++m)
                #pragma unroll
                for (int s = 0; s < SG; ++s)
                    ob[s][kr + 16 * m] = acc[m][s];
        }
        __syncthreads();                      // ob visible
        {   // write: thread t -> k = k0 + (t&63), samples (t>>6)*4+ss
            const int j = t & 63;
            #pragma unroll
            for (int ss = 0; ss < 4; ++ss) {
                const int s = (t >> 6) * 4 + ss;
                if (s < gs)
                    P[(size_t)v * BH + (size_t)slist[g0 + s] * HID + k0 + j] = ob[s][j];
            }
        }
    }
}

// ---------------------------------------------------------------------------
// k3: assemble out.  out[b,k] = sum_{v>=k>>8} P[v][b][k] + d_k t_k
//                              + 1e-3 (Tt - t_k).  One block per sample.
// ---------------------------------------------------------------------------
__global__ __launch_bounds__(256) void k3(
    const int* __restrict__ y, const float* __restrict__ M,
    const float* __restrict__ T, const float* __restrict__ P,
    float* __restrict__ out)
{
    const int b = blockIdx.x, t = threadIdx.x;
    const int c = y[b];
    __shared__ float wred[4];

    const size_t bh = (size_t)b * HID;
    const float t0 = T[bh + t], t1 = T[bh + t + 256], t2 = T[bh + t + 512];
    float st = t0 + t1 + t2;
    #pragma unroll
    for (int off = 32; off; off >>= 1) st += __shfl_xor(st, off);
    if ((t & 63) == 0) wred[t >> 6] = st;
    __syncthreads();
    const float Tt = (wred[0] + wred[1]) + (wred[2] + wred[3]);

    const float* __restrict__ Mc = M + (size_t)c * HID * HID;
    const float p0 = P[bh + t] + P[(size_t)BH + bh + t] + P[2 * (size_t)BH + bh + t];
    const float p1 = P[(size_t)BH + bh + t + 256] + P[2 * (size_t)BH + bh + t + 256];
    const float p2 = P[2 * (size_t)BH + bh + t + 512];
    const float pp[3] = {p0, p1, p2};
    const float tv[3] = {t0, t1, t2};
    #pragma unroll
    for (int qi = 0; qi < 3; ++qi) {
        const int k = t + 256 * qi;
        const float dk = fmaxf(Mc[(size_t)k * (HID + 1)], 1e-3f);
        out[bh + k] = pp[qi] + dk * tv[qi] + 1e-3f * (Tt - tv[qi]);
    }
}

extern "C" void kernel_launch(void* const* d_in, const int* in_sizes, int n_in,
                              void* d_out, int out_size, void* d_ws, size_t ws_size,
                              hipStream_t stream) {
    const float* x = (const float*)d_in[0];
    const int*   y = (const int*)d_in[1];
    const float* M = (const float*)d_in[2];
    float* out = (float*)d_out;
    float* Tp  = (float*)d_ws;                 // 3 x BH floats (4.5 MiB)
    float* T   = (float*)d_ws + 3 * (size_t)BH; // 1 x BH (1.5 MiB)
    float* P   = (float*)d_ws + 4 * (size_t)BH; // 3 x BH (4.5 MiB)

    kA<<<dim3(NCLASS, 24), 256, 0, stream>>>(x, y, M, Tp);
    kT<<<dim3(BATCH), 256, 0, stream>>>(x, y, M, Tp, T);
    kB<<<dim3(NCLASS, 24), 256, 0, stream>>>(y, M, T, P);
    k3<<<dim3(BATCH), 256, 0, stream>>>(y, M, T, P, out);
}

// Round 9
// 120.725 us; speedup vs baseline: 1.5901x; 1.2121x over previous
//
#include <hip/hip_runtime.h>

#define NCLASS 100
#define HID    768
#define BATCH  512
#define SG     8
#define BH     (BATCH * HID)

// kA uniform tiles (verified round 8): column panel g (64 cols), row slice h
// (256 rows), big-work-first.
__constant__ int gA_tab[24] = {3,4,5,6,7,7,8,8,9,9,10,10,11,11,11, 2,6,10, 1,5,9, 0,4,8};
__constant__ int hA_tab[24] = {0,0,0,0,0,1,0,1,0,1, 0, 1, 0, 1, 2, 0,1, 2, 0,1,2, 0,1,2};

// ---------------------------------------------------------------------------
// k0: per-class sample lists, per-sample x row-sums X[b], per-class diag
// vectors D[c][j] = max(M[j,j], 1e-3).  Grid 109 blocks.
// ---------------------------------------------------------------------------
__global__ __launch_bounds__(256) void k0(
    const float* __restrict__ x, const int* __restrict__ y,
    const float* __restrict__ M,
    int* __restrict__ slist_g, int* __restrict__ scnt_g,
    float* __restrict__ Xs_g, float* __restrict__ D_g)
{
    const int bb = blockIdx.x, t = threadIdx.x;
    if (bb < NCLASS) {
        const float* __restrict__ Mc = M + (size_t)bb * HID * HID;
        #pragma unroll
        for (int qi = 0; qi < 3; ++qi) {
            const int j = t + 256 * qi;
            D_g[bb * HID + j] = fmaxf(Mc[(size_t)j * (HID + 1)], 1e-3f);
        }
    } else if (bb == NCLASS) {
        if (t < 64) {
            for (int c = 0; c < NCLASS; ++c) {
                int n = 0;
                for (int r = 0; r < BATCH / 64; ++r) {
                    const int b = r * 64 + t;
                    const bool hit = (y[b] == c);
                    const unsigned long long mask = __ballot(hit);
                    if (hit) slist_g[c * 64 + n + __popcll(mask & ((1ull << t) - 1ull))] = b;
                    n += __popcll(mask);
                }
                if (t == 0) scnt_g[c] = n;
            }
        }
    } else {
        const int s0 = (bb - NCLASS - 1) * 64;
        const int sl = t >> 2, qq = t & 3;
        const int b = s0 + sl;
        const float4* __restrict__ xr = (const float4*)(x + (size_t)b * HID);
        float p = 0.f;
        for (int i = 0; i < 48; ++i) {
            const float4 v = xr[qq * 48 + i];
            p += (v.x + v.y) + (v.z + v.w);
        }
        p += __shfl_xor(p, 1);
        p += __shfl_xor(p, 2);
        if (qq == 0) Xs_g[b] = p;
    }
}

// ---------------------------------------------------------------------------
// kA: partial t.  Tp[h][b][col0+j] = sum over rows [256h, ...) of
// x[b,row]*M[row, col0+j] (strict row<col in the diagonal square).
// hg=t>>4 (16 rows/chunk), jq=t&15; SG=8 samples; 64-row chunks (4 loads).
// ---------------------------------------------------------------------------
__global__ __launch_bounds__(256, 5) void kA(
    const float* __restrict__ x, const int* __restrict__ slist_g,
    const int* __restrict__ scnt_g, const float* __restrict__ M,
    float* __restrict__ Tp)
{
    const int t    = threadIdx.x;
    const int c    = blockIdx.x;
    const int g    = gA_tab[blockIdx.y], h = hA_tab[blockIdx.y];
    const int col0 = g * 64, row0 = h * 256;
    const bool hasdiag = (h == (g >> 2));
    const int rows = min(256, 64 * (g + 1) - row0);
    const int bulk = hasdiag ? rows - 64 : rows;
    const int cnt  = scnt_g[c];
    if (cnt == 0) return;

    __shared__ float xs[SG][256];            // 8 KB
    __shared__ float red[4][16][4][SG + 1];  // 9.2 KB, padded

    const float* __restrict__ Mc   = M + (size_t)c * HID * HID;
    const float* __restrict__ Mpan = Mc + (size_t)row0 * HID + col0 + (t & 15) * 4;
    const int hg = t >> 4, jq = t & 15, wv = t >> 6, ln = t & 63;

    for (int g0 = 0; g0 < cnt; g0 += SG) {
        const int gs = min(SG, cnt - g0);
        __syncthreads();                      // prev group fully done
        {   // stage x rows [row0, row0+256): sample s = t>>5, 32 threads each
            const int s = t >> 5, l = t & 31;
            const int b = slist_g[c * 64 + g0 + (s < gs ? s : 0)];
            const float4* xr = (const float4*)(x + (size_t)b * HID + row0);
            *(float4*)&xs[s][l * 8]     = xr[l * 2];
            *(float4*)&xs[s][l * 8 + 4] = xr[l * 2 + 1];
        }
        __syncthreads();

        float tp[4][SG];
        #pragma unroll
        for (int jj = 0; jj < 4; ++jj)
            #pragma unroll
            for (int s = 0; s < SG; ++s) tp[jj][s] = 0.f;

        for (int r = 0; r < bulk; r += 64) {  // 4 loads in flight
            float4 ma[4];
            #pragma unroll
            for (int m = 0; m < 4; ++m)
                ma[m] = *(const float4*)(Mpan + (size_t)(r + hg + 16 * m) * HID);
            #pragma unroll
            for (int m = 0; m < 4; ++m) {
                const int lr = r + hg + 16 * m;
                #pragma unroll
                for (int s = 0; s < SG; ++s) {
                    const float xv = xs[s][lr];
                    tp[0][s] = fmaf(xv, ma[m].x, tp[0][s]);
                    tp[1][s] = fmaf(xv, ma[m].y, tp[1][s]);
                    tp[2][s] = fmaf(xv, ma[m].z, tp[2][s]);
                    tp[3][s] = fmaf(xv, ma[m].w, tp[3][s]);
                }
            }
        }
        if (hasdiag) {                        // diagonal square: strict row<col
            float4 ma[4];
            #pragma unroll
            for (int m = 0; m < 4; ++m) {
                const int hrel = hg + 16 * m;
                ma[m] = *(const float4*)(Mpan + (size_t)(bulk + hrel) * HID);
                if (4 * jq + 0 <= hrel) ma[m].x = 0.f;
                if (4 * jq + 1 <= hrel) ma[m].y = 0.f;
                if (4 * jq + 2 <= hrel) ma[m].z = 0.f;
                if (4 * jq + 3 <= hrel) ma[m].w = 0.f;
            }
            #pragma unroll
            for (int m = 0; m < 4; ++m) {
                const int lr = bulk + hg + 16 * m;
                #pragma unroll
                for (int s = 0; s < SG; ++s) {
                    const float xv = xs[s][lr];
                    tp[0][s] = fmaf(xv, ma[m].x, tp[0][s]);
                    tp[1][s] = fmaf(xv, ma[m].y, tp[1][s]);
                    tp[2][s] = fmaf(xv, ma[m].z, tp[2][s]);
                    tp[3][s] = fmaf(xv, ma[m].w, tp[3][s]);
                }
            }
        }
        // reduce 4 hg-subgroups within each wave (lane bits 4,5)
        #pragma unroll
        for (int mm = 16; mm <= 32; mm <<= 1)
            #pragma unroll
            for (int jj = 0; jj < 4; ++jj)
                #pragma unroll
                for (int s = 0; s < SG; ++s)
                    tp[jj][s] += __shfl_xor(tp[jj][s], mm);
        if (ln < 16) {
            #pragma unroll
            for (int jj = 0; jj < 4; ++jj)
                #pragma unroll
                for (int s = 0; s < SG; ++s)
                    red[wv][ln][jj][s] = tp[jj][s];
        }
        __syncthreads();                      // red visible
        {   // write: col j=t&63, samples (t>>6)*2+ss
            const int j = t & 63, jq2 = j >> 2, jj2 = j & 3;
            #pragma unroll
            for (int ss = 0; ss < 2; ++ss) {
                const int s = (t >> 6) * 2 + ss;
                if (s < gs) {
                    const float u = (red[0][jq2][jj2][s] + red[1][jq2][jj2][s])
                                  + (red[2][jq2][jj2][s] + red[3][jq2][jj2][s]);
                    Tp[(size_t)h * BH + (size_t)slist_g[c * 64 + g0 + s] * HID + col0 + j] = u;
                }
            }
        }
    }
}

// ---------------------------------------------------------------------------
// kB: out[b,k] for k in 64-row panel K=[64q,64q+64), b in class c.
// Staging MERGES t in place: t[b,j] = sum_{slices} Tp[h][b][j]
//   + D[c][j] x[b,j] + 1e-3 (X[b] - x[b,j])   (slices per 256-range: 1/2/3).
// Then streams M rows k, cols j>k (peeled diag + branch-free bulk) and
// writes out with the d_k / 1e-3 epilogue.  kr=t>>4, cg=t&15.
// ---------------------------------------------------------------------------
__global__ __launch_bounds__(256, 4) void kB(
    const float* __restrict__ x, const int* __restrict__ slist_g,
    const int* __restrict__ scnt_g, const float* __restrict__ M,
    const float* __restrict__ Tp, const float* __restrict__ Xs_g,
    const float* __restrict__ D_g, float* __restrict__ out)
{
    const int t  = threadIdx.x;
    const int c  = blockIdx.x;
    const int q  = blockIdx.y;                // q=0 (biggest) first
    const int k0 = q * 64;
    const int cnt = scnt_g[c];
    if (cnt == 0) return;

    __shared__ float ts[SG][HID];             // 24 KB
    __shared__ float dl[HID];                 // 3 KB
    __shared__ float Tt[SG];
    __shared__ float ob[SG][65];

    if (t < 192) *(float4*)&dl[t * 4] = ((const float4*)(D_g + c * HID))[t];

    const float* __restrict__ Mc = M + (size_t)c * HID * HID;
    const int kr = t >> 4, cg = t & 15;
    const float* __restrict__ r0 = Mc + (size_t)(k0 + kr     ) * HID + k0 + cg * 4;
    const float* __restrict__ r1 = Mc + (size_t)(k0 + kr + 16) * HID + k0 + cg * 4;
    const float* __restrict__ r2 = Mc + (size_t)(k0 + kr + 32) * HID + k0 + cg * 4;
    const float* __restrict__ r3 = Mc + (size_t)(k0 + kr + 48) * HID + k0 + cg * 4;

    for (int g0 = 0; g0 < cnt; g0 += SG) {
        const int gs = min(SG, cnt - g0);
        __syncthreads();                      // prev group done; dl visible
        {   // stage merged t: sample s = t>>5, 32 threads x 6 float4 each
            const int s = t >> 5, l = t & 31;
            const int b = slist_g[c * 64 + g0 + (s < gs ? s : 0)];
            const size_t bh4 = (size_t)b * (HID / 4);
            const float4* __restrict__ x4 = (const float4*)x;
            const float4* __restrict__ T0 = (const float4*)Tp;
            const float4* __restrict__ T1 = (const float4*)(Tp + (size_t)BH);
            const float4* __restrict__ T2 = (const float4*)(Tp + 2 * (size_t)BH);
            const float Xb = Xs_g[b];
            float psum = 0.f;
            #pragma unroll
            for (int r = 0; r < 3; ++r) {
                #pragma unroll
                for (int u = 0; u < 2; ++u) {
                    const int j4 = r * 64 + l * 2 + u;
                    float4 tv = T0[bh4 + j4];
                    if (r >= 1) {
                        const float4 a = T1[bh4 + j4];
                        tv.x += a.x; tv.y += a.y; tv.z += a.z; tv.w += a.w;
                    }
                    if (r >= 2) {
                        const float4 a = T2[bh4 + j4];
                        tv.x += a.x; tv.y += a.y; tv.z += a.z; tv.w += a.w;
                    }
                    const float4 xv = x4[bh4 + j4];
                    const float4 dv = *(const float4*)&dl[j4 * 4];
                    float4 o;
                    o.x = tv.x + dv.x * xv.x + 1e-3f * (Xb - xv.x);
                    o.y = tv.y + dv.y * xv.y + 1e-3f * (Xb - xv.y);
                    o.z = tv.z + dv.z * xv.z + 1e-3f * (Xb - xv.z);
                    o.w = tv.w + dv.w * xv.w + 1e-3f * (Xb - xv.w);
                    *(float4*)&ts[s][j4 * 4] = o;
                    psum += (o.x + o.y) + (o.z + o.w);
                }
            }
            #pragma unroll
            for (int off = 1; off <= 16; off <<= 1) psum += __shfl_xor(psum, off);
            if (l == 0) Tt[s] = psum;
        }
        __syncthreads();                      // ts, Tt visible

        float acc[4][SG];
        #pragma unroll
        for (int m = 0; m < 4; ++m)
            #pragma unroll
            for (int s = 0; s < SG; ++s) acc[m][s] = 0.f;

        {   // peeled diag-crossing chunk (cols k0..k0+63): keep j>k only
            const int j0 = k0 + cg * 4;
            float4 mq[4];
            mq[0] = *(const float4*)(r0);
            mq[1] = *(const float4*)(r1);
            mq[2] = *(const float4*)(r2);
            mq[3] = *(const float4*)(r3);
            #pragma unroll
            for (int m = 0; m < 4; ++m) {
                const int k = k0 + 16 * m + kr;
                if (j0 + 0 <= k) mq[m].x = 0.f;
                if (j0 + 1 <= k) mq[m].y = 0.f;
                if (j0 + 2 <= k) mq[m].z = 0.f;
                if (j0 + 3 <= k) mq[m].w = 0.f;
            }
            #pragma unroll
            for (int s = 0; s < SG; ++s) {
                const float4 tv = *(const float4*)&ts[s][j0];
                #pragma unroll
                for (int m = 0; m < 4; ++m) {
                    acc[m][s] = fmaf(mq[m].x, tv.x, acc[m][s]);
                    acc[m][s] = fmaf(mq[m].y, tv.y, acc[m][s]);
                    acc[m][s] = fmaf(mq[m].z, tv.z, acc[m][s]);
                    acc[m][s] = fmaf(mq[m].w, tv.w, acc[m][s]);
                }
            }
        }
        int jb = k0 + 64;
        for (; jb + 128 <= HID; jb += 128) {  // 8 loads in flight
            float4 ma[4], mb[4];
            ma[0] = *(const float4*)(r0 + (jb - k0));
            ma[1] = *(const float4*)(r1 + (jb - k0));
            ma[2] = *(const float4*)(r2 + (jb - k0));
            ma[3] = *(const float4*)(r3 + (jb - k0));
            mb[0] = *(const float4*)(r0 + (jb - k0) + 64);
            mb[1] = *(const float4*)(r1 + (jb - k0) + 64);
            mb[2] = *(const float4*)(r2 + (jb - k0) + 64);
            mb[3] = *(const float4*)(r3 + (jb - k0) + 64);
            const int j0 = jb + cg * 4;
            #pragma unroll
            for (int s = 0; s < SG; ++s) {
                const float4 tv = *(const float4*)&ts[s][j0];
                #pragma unroll
                for (int m = 0; m < 4; ++m) {
                    acc[m][s] = fmaf(ma[m].x, tv.x, acc[m][s]);
                    acc[m][s] = fmaf(ma[m].y, tv.y, acc[m][s]);
                    acc[m][s] = fmaf(ma[m].z, tv.z, acc[m][s]);
                    acc[m][s] = fmaf(ma[m].w, tv.w, acc[m][s]);
                }
            }
            #pragma unroll
            for (int s = 0; s < SG; ++s) {
                const float4 tv = *(const float4*)&ts[s][j0 + 64];
                #pragma unroll
                for (int m = 0; m < 4; ++m) {
                    acc[m][s] = fmaf(mb[m].x, tv.x, acc[m][s]);
                    acc[m][s] = fmaf(mb[m].y, tv.y, acc[m][s]);
                    acc[m][s] = fmaf(mb[m].z, tv.z, acc[m][s]);
                    acc[m][s] = fmaf(mb[m].w, tv.w, acc[m][s]);
                }
            }
        }
        if (jb < HID) {                       // one remaining 64-col chunk
            float4 ma[4];
            ma[0] = *(const float4*)(r0 + (jb - k0));
            ma[1] = *(const float4*)(r1 + (jb - k0));
            ma[2] = *(const float4*)(r2 + (jb - k0));
            ma[3] = *(const float4*)(r3 + (jb - k0));
            const int j0 = jb + cg * 4;
            #pragma unroll
            for (int s = 0; s < SG; ++s) {
                const float4 tv = *(const float4*)&ts[s][j0];
                #pragma unroll
                for (int m = 0; m < 4; ++m) {
                    acc[m][s] = fmaf(ma[m].x, tv.x, acc[m][s]);
                    acc[m][s] = fmaf(ma[m].y, tv.y, acc[m][s]);
                    acc[m][s] = fmaf(ma[m].z, tv.z, acc[m][s]);
                    acc[m][s] = fmaf(ma[m].w, tv.w, acc[m][s]);
                }
            }
        }
        // reduce 16 col-quads (lane bits 0..3)
        #pragma unroll
        for (int mm = 1; mm <= 8; mm <<= 1)
            #pragma unroll
            for (int m = 0; m < 4; ++m)
                #pragma unroll
                for (int s = 0; s < SG; ++s)
                    acc[m][s] += __shfl_xor(acc[m][s], mm);
        if (cg == 0) {
            #pragma unroll
            for (int m = 0; m < 4; ++m)
                #pragma unroll
                for (int s = 0; s < SG; ++s)
                    ob[s][16 * m + kr] = acc[m][s];
        }
        __syncthreads();                      // ob visible
        {   // write out with epilogue terms
            const int j = t & 63;
            const int k = k0 + j;
            #pragma unroll
            for (int ss = 0; ss < 2; ++ss) {
                const int s = (t >> 6) * 2 + ss;
                if (s < gs) {
                    const float tk = ts[s][k];
                    out[(size_t)slist_g[c * 64 + g0 + s] * HID + k] =
                        ob[s][j] + dl[k] * tk + 1e-3f * (Tt[s] - tk);
                }
            }
        }
    }
}

extern "C" void kernel_launch(void* const* d_in, const int* in_sizes, int n_in,
                              void* d_out, int out_size, void* d_ws, size_t ws_size,
                              hipStream_t stream) {
    const float* x = (const float*)d_in[0];
    const int*   y = (const int*)d_in[1];
    const float* M = (const float*)d_in[2];
    float* out = (float*)d_out;

    float* Tp      = (float*)d_ws;                       // 3*BH floats (4.5 MiB)
    int*   slist_g = (int*)((float*)d_ws + 3 * (size_t)BH);
    int*   scnt_g  = slist_g + NCLASS * 64;
    float* Xs_g    = (float*)(scnt_g + 128);
    float* D_g     = Xs_g + BATCH;

    k0<<<dim3(NCLASS + 1 + BATCH / 64), 256, 0, stream>>>(x, y, M, slist_g, scnt_g, Xs_g, D_g);
    kA<<<dim3(NCLASS, 24), 256, 0, stream>>>(x, slist_g, scnt_g, M, Tp);
    kB<<<dim3(NCLASS, 12), 256, 0, stream>>>(x, slist_g, scnt_g, M, Tp, Xs_g, D_g, out);
}

// Round 10
// 80.855 us; speedup vs baseline: 2.3742x; 1.4931x over previous
//
#include <hip/hip_runtime.h>

#define NCLASS 100
#define HID    768
#define BATCH  512
#define SG     8
#define NPAN   12      // 12 panels of 64 columns/rows

// Deterministic per-class sample list (wave 0 of each block).
__device__ __forceinline__ void build_list(const int* __restrict__ y, int c,
                                           int* slist, int* scnt, int t) {
    if (t < 64) {
        int n = 0;
        for (int r = 0; r < BATCH / 64; ++r) {
            const int b = r * 64 + t;
            const bool hit = (y[b] == c);
            const unsigned long long mask = __ballot(hit);
            if (hit) slist[n + __popcll(mask & ((1ull << t) - 1ull))] = b;
            n += __popcll(mask);
        }
        if (t == 0) *scnt = n;
    }
}

// ---------------------------------------------------------------------------
// Kernel A: t[b, j] for j in 64-col panel J=[64g, 64g+64), b in class c.
//   t_j = sum_{h<j} x_h M[h,j] + d_j x_j + 1e-3 (X - x_j), d_j=max(M[j,j],1e-3)
// GRID IS (NPAN, NCLASS): panel index is blockIdx.x (fastest-dispatching), so
// one class's 12 strip-blocks run concurrently; their union sweeps full rows
// of the triangle sequentially -> DRAM row-buffer-friendly aggregate pattern.
// Thread map: hg = t>>4 (16 rows/chunk), jq = t&15 (16 col-quads).
// ---------------------------------------------------------------------------
__global__ __launch_bounds__(256, 4) void kA(
    const float* __restrict__ x, const int* __restrict__ y,
    const float* __restrict__ M, float* __restrict__ T)
{
    const int c    = blockIdx.y;
    const int g    = (NPAN - 1) - blockIdx.x;   // big panels dispatch first
    const int t    = threadIdx.x;
    const int col0 = g * 64;

    __shared__ int   slist[BATCH];
    __shared__ int   scnt;
    __shared__ float xs[SG][HID];         // 24 KB
    __shared__ float Xs[SG];
    __shared__ float red[4][16][4][SG];   // [wave][jq][jj][s]  8 KB
    __shared__ float dj_lds[64];

    build_list(y, c, slist, &scnt, t);
    __syncthreads();
    const int cnt = scnt;
    if (cnt == 0) return;

    const float* __restrict__ Mc = M + (size_t)c * HID * HID;
    const int wv = t >> 6, ln = t & 63;
    const int hg = t >> 4, jq = t & 15;

    if (t < 64) {
        const int jg = col0 + t;
        dj_lds[t] = fmaxf(Mc[(size_t)jg * HID + jg], 1e-3f);
    }

    for (int g0 = 0; g0 < cnt; g0 += SG) {
        const int gs = min(SG, cnt - g0);
        __syncthreads();                      // prev group done; dj_lds visible
        // stage x rows: wave wv stages samples 2wv, 2wv+1; also row-sums X
        #pragma unroll
        for (int ss = 0; ss < 2; ++ss) {
            const int s = 2 * wv + ss;
            const int b = slist[g0 + (s < gs ? s : 0)];
            const float4* xr = (const float4*)(x + (size_t)b * HID);
            const float4 v0 = xr[ln], v1 = xr[ln + 64], v2 = xr[ln + 128];
            *(float4*)&xs[s][ln * 4]       = v0;
            *(float4*)&xs[s][ln * 4 + 256] = v1;
            *(float4*)&xs[s][ln * 4 + 512] = v2;
            float pX = ((v0.x + v0.y) + (v0.z + v0.w))
                     + ((v1.x + v1.y) + (v1.z + v1.w))
                     + ((v2.x + v2.y) + (v2.z + v2.w));
            #pragma unroll
            for (int off = 32; off; off >>= 1) pX += __shfl_xor(pX, off);
            if (ln == 0) Xs[s] = pX;
        }
        __syncthreads();                      // xs, Xs visible

        float tp[4][SG];
        #pragma unroll
        for (int jj = 0; jj < 4; ++jj)
            #pragma unroll
            for (int s = 0; s < SG; ++s) tp[jj][s] = 0.f;

        for (int h = hg; h < col0 + 16; h += 16) { /* placeholder no-op guard */ }

        for (int hb = 0; hb < col0; hb += 64) {   // bulk rows h < col0
            float4 ma[4];
            #pragma unroll
            for (int m = 0; m < 4; ++m)
                ma[m] = *(const float4*)(Mc + (size_t)(hb + hg + 16 * m) * HID + col0 + jq * 4);
            #pragma unroll
            for (int m = 0; m < 4; ++m) {
                const int h = hb + hg + 16 * m;
                #pragma unroll
                for (int s = 0; s < SG; ++s) {
                    const float xv = xs[s][h];
                    tp[0][s] = fmaf(xv, ma[m].x, tp[0][s]);
                    tp[1][s] = fmaf(xv, ma[m].y, tp[1][s]);
                    tp[2][s] = fmaf(xv, ma[m].z, tp[2][s]);
                    tp[3][s] = fmaf(xv, ma[m].w, tp[3][s]);
                }
            }
        }
        {   // peeled diagonal 64-row square: strict h<j masks
            float4 ma[4];
            #pragma unroll
            for (int m = 0; m < 4; ++m) {
                const int hrel = hg + 16 * m;
                ma[m] = *(const float4*)(Mc + (size_t)(col0 + hrel) * HID + col0 + jq * 4);
                if (4 * jq + 0 <= hrel) ma[m].x = 0.f;
                if (4 * jq + 1 <= hrel) ma[m].y = 0.f;
                if (4 * jq + 2 <= hrel) ma[m].z = 0.f;
                if (4 * jq + 3 <= hrel) ma[m].w = 0.f;
            }
            #pragma unroll
            for (int m = 0; m < 4; ++m) {
                const int h = col0 + hg + 16 * m;
                #pragma unroll
                for (int s = 0; s < SG; ++s) {
                    const float xv = xs[s][h];
                    tp[0][s] = fmaf(xv, ma[m].x, tp[0][s]);
                    tp[1][s] = fmaf(xv, ma[m].y, tp[1][s]);
                    tp[2][s] = fmaf(xv, ma[m].z, tp[2][s]);
                    tp[3][s] = fmaf(xv, ma[m].w, tp[3][s]);
                }
            }
        }
        // reduce the 4 row-groups within each wave (lane bits 4,5)
        #pragma unroll
        for (int m = 16; m <= 32; m <<= 1)
            #pragma unroll
            for (int jj = 0; jj < 4; ++jj)
                #pragma unroll
                for (int s = 0; s < SG; ++s)
                    tp[jj][s] += __shfl_xor(tp[jj][s], m);
        if (ln < 16) {
            #pragma unroll
            for (int jj = 0; jj < 4; ++jj)
                #pragma unroll
                for (int s = 0; s < SG; ++s)
                    red[wv][ln][jj][s] = tp[jj][s];
        }
        __syncthreads();                      // red visible
        // finalize: thread t handles col j = t&63 for 2 samples
        {
            const int j = t & 63, jq2 = j >> 2, jj2 = j & 3;
            const int jg = col0 + j;
            #pragma unroll
            for (int ss = 0; ss < 2; ++ss) {
                const int s = (t >> 6) * 2 + ss;
                if (s < gs) {
                    const float u = (red[0][jq2][jj2][s] + red[1][jq2][jj2][s])
                                  + (red[2][jq2][jj2][s] + red[3][jq2][jj2][s]);
                    const float xj = xs[s][jg];
                    T[(size_t)slist[g0 + s] * HID + jg] =
                        u + dj_lds[j] * xj + 1e-3f * (Xs[s] - xj);
                }
            }
        }
    }
}

// ---------------------------------------------------------------------------
// Kernel B: out[b, k] for k in 64-row panel K=[64q, 64q+64), b in class c.
//   out_k = sum_{j>k} M[k,j] t_j + d_k t_k + 1e-3 (Tt - t_k)
// GRID IS (NPAN, NCLASS): q = blockIdx.x (q=0, biggest, dispatches first);
// one class's 12 row-panel blocks run concurrently (L3-clustered re-reads).
// Thread map: kr = t>>4 (16 rows x 4 m-chunks), cg = t&15 (16 col-quads).
// ---------------------------------------------------------------------------
__global__ __launch_bounds__(256, 4) void kB(
    const int* __restrict__ y, const float* __restrict__ M,
    const float* __restrict__ T, float* __restrict__ out)
{
    const int c  = blockIdx.y;
    const int q  = blockIdx.x;
    const int t  = threadIdx.x;
    const int k0 = q * 64;

    __shared__ int   slist[BATCH];
    __shared__ int   scnt;
    __shared__ float ts[SG][HID];         // 24 KB
    __shared__ float Tt[SG];
    __shared__ float ob[SG][64];          // 2 KB
    __shared__ float dk_lds[64];

    build_list(y, c, slist, &scnt, t);
    __syncthreads();
    const int cnt = scnt;
    if (cnt == 0) return;

    const float* __restrict__ Mc = M + (size_t)c * HID * HID;
    const int wv = t >> 6, ln = t & 63;
    const int kr = t >> 4, cg = t & 15;

    if (t < 64) {
        const int kg = k0 + t;
        dk_lds[t] = fmaxf(Mc[(size_t)kg * HID + kg], 1e-3f);
    }

    for (int g0 = 0; g0 < cnt; g0 += SG) {
        const int gs = min(SG, cnt - g0);
        __syncthreads();                      // prev group done (ob reads done)
        // stage t rows: wave wv stages samples 2wv, 2wv+1; also row-sums Tt
        #pragma unroll
        for (int ss = 0; ss < 2; ++ss) {
            const int s = 2 * wv + ss;
            const int b = slist[g0 + (s < gs ? s : 0)];
            const float4* tr = (const float4*)(T + (size_t)b * HID);
            const float4 v0 = tr[ln], v1 = tr[ln + 64], v2 = tr[ln + 128];
            *(float4*)&ts[s][ln * 4]       = v0;
            *(float4*)&ts[s][ln * 4 + 256] = v1;
            *(float4*)&ts[s][ln * 4 + 512] = v2;
            float pT = ((v0.x + v0.y) + (v0.z + v0.w))
                     + ((v1.x + v1.y) + (v1.z + v1.w))
                     + ((v2.x + v2.y) + (v2.z + v2.w));
            #pragma unroll
            for (int off = 32; off; off >>= 1) pT += __shfl_xor(pT, off);
            if (ln == 0) Tt[s] = pT;
        }
        __syncthreads();                      // ts, Tt visible

        float acc[4][SG];
        #pragma unroll
        for (int m = 0; m < 4; ++m)
            #pragma unroll
            for (int s = 0; s < SG; ++s) acc[m][s] = 0.f;

        for (int jb = k0; jb < HID; jb += 64) {
            const int j0 = jb + cg * 4;
            float4 mq[4];
            #pragma unroll
            for (int m = 0; m < 4; ++m) {
                const int k = k0 + 16 * m + kr;
                mq[m] = *(const float4*)(Mc + (size_t)k * HID + j0);
                if (jb == k0) {               // diag-crossing chunk: keep j>k
                    if (j0 + 0 <= k) mq[m].x = 0.f;
                    if (j0 + 1 <= k) mq[m].y = 0.f;
                    if (j0 + 2 <= k) mq[m].z = 0.f;
                    if (j0 + 3 <= k) mq[m].w = 0.f;
                }
            }
            #pragma unroll
            for (int s = 0; s < SG; ++s) {
                const float4 tv = *(const float4*)&ts[s][j0];
                #pragma unroll
                for (int m = 0; m < 4; ++m) {
                    acc[m][s] = fmaf(mq[m].x, tv.x, acc[m][s]);
                    acc[m][s] = fmaf(mq[m].y, tv.y, acc[m][s]);
                    acc[m][s] = fmaf(mq[m].z, tv.z, acc[m][s]);
                    acc[m][s] = fmaf(mq[m].w, tv.w, acc[m][s]);
                }
            }
        }
        // reduce over the 16 col-quads (lane bits 0..3)
        #pragma unroll
        for (int m2 = 1; m2 <= 8; m2 <<= 1)
            #pragma unroll
            for (int m = 0; m < 4; ++m)
                #pragma unroll
                for (int s = 0; s < SG; ++s)
                    acc[m][s] += __shfl_xor(acc[m][s], m2);
        if (cg == 0) {
            #pragma unroll
            for (int m = 0; m < 4; ++m)
                #pragma unroll
                for (int s = 0; s < SG; ++s)
                    ob[s][16 * m + kr] = acc[m][s];
        }
        __syncthreads();                      // ob visible
        // store: thread t handles k = k0 + (t&63) for 2 samples
        {
            const int j = t & 63;
            const int k = k0 + j;
            #pragma unroll
            for (int ss = 0; ss < 2; ++ss) {
                const int s = (t >> 6) * 2 + ss;
                if (s < gs) {
                    const float tk = ts[s][k];
                    out[(size_t)slist[g0 + s] * HID + k] =
                        ob[s][j] + dk_lds[j] * tk + 1e-3f * (Tt[s] - tk);
                }
            }
        }
    }
}

extern "C" void kernel_launch(void* const* d_in, const int* in_sizes, int n_in,
                              void* d_out, int out_size, void* d_ws, size_t ws_size,
                              hipStream_t stream) {
    const float* x = (const float*)d_in[0];
    const int*   y = (const int*)d_in[1];
    const float* M = (const float*)d_in[2];
    float* out = (float*)d_out;
    float* T   = (float*)d_ws;   // 512 * 768 * 4 B = 1.5 MiB scratch

    kA<<<dim3(NPAN, NCLASS), 256, 0, stream>>>(x, y, M, T);
    kB<<<dim3(NPAN, NCLASS), 256, 0, stream>>>(y, M, T, out);
}